// Round 1
// 121.286 us; speedup vs baseline: 1.0544x; 1.0544x over previous
//
#include <hip/hip_runtime.h>
#include <hip/hip_bf16.h>
#include <stdint.h>

// VQ-VAE vector quantizer forward, MI355X (gfx950).
// z: [32,256,32,32] fp32 (NCHW), E: [1024,256] fp32.
// score(n,k) = 0.5*||e_k||^2 - <f_n,e_k>  (argmin-equivalent to d2)
// dots via bf16 MFMA 16x16x32 fp32-accum; gather exact fp32.
//
// R6: fuse k_prep_a into k_main. The block's 128x256 z-tile is register-
// transposed (k_prep_a's float4-along-hw trick) straight into the idle S
// union as a bf16 A-tile (XOR swizzle slot^=(row^row>>2)&7: both d-major
// writes and fragment reads sit at the ds_*_b128 bank floor). Loss no
// longer re-reads z: ||e-z||^2 = 2*s* + ||z||^2, with ||z||^2 computed
// from the bf16 fragments (error ~1e-6 on the final scalars). HBM traffic
// drops 134->68 MB and one kernel launch disappears.

typedef short v8s __attribute__((ext_vector_type(8)));
typedef float v4f __attribute__((ext_vector_type(4)));

__device__ inline unsigned short f2bf(float f) {  // RNE fp32->bf16
    uint32_t u = __float_as_uint(f);
    return (unsigned short)((u + 0x7fffu + ((u >> 16) & 1u)) >> 16);
}

// ---- Kernel 1: E -> SWIZZLED Ebf bf16 + nE + accum=0 -----------------------
// Unit for (k, dc, g): U = (k>>4)*512 + dc*64 + g*16 + (k&15),
// holding elems d = dc*32 + g*8 .. +8. Coalesced 16B stores.
__global__ __launch_bounds__(256) void k_prep_e(const float* __restrict__ E,
                                                v8s* __restrict__ Esw,
                                                float* __restrict__ nE,
                                                float* __restrict__ accum) {
    __shared__ float Ef[16][264];
    int q = blockIdx.x, tid = threadIdx.x;
    const float4* Ein = (const float4*)(E + ((size_t)q << 12));
#pragma unroll
    for (int i = 0; i < 4; i++) {
        int f4 = i * 256 + tid;
        int row = f4 >> 6, c4 = (f4 & 63) << 2;
        *(float4*)&Ef[row][c4] = Ein[f4];
    }
    __syncthreads();
    {
        int c = tid >> 4, l = tid & 15;
        float s = 0.f;
#pragma unroll
        for (int j = 0; j < 16; j++) { float v = Ef[c][l + 16 * j]; s += v * v; }
#pragma unroll
        for (int off = 1; off < 16; off <<= 1) s += __shfl_xor(s, off);
        if (l == 0) nE[q * 16 + c] = 0.5f * s;
    }
#pragma unroll
    for (int i = 0; i < 2; i++) {
        int u = tid + i * 256;
        int um = u & 15, ug = (u >> 4) & 3, udc = (u >> 6) & 7;
        int d0 = udc * 32 + ug * 8;
        union { v8s v; unsigned short s[8]; } pk;
#pragma unroll
        for (int e = 0; e < 8; e++) pk.s[e] = f2bf(Ef[um][d0 + e]);
        Esw[((size_t)q << 9) + u] = pk.v;
    }
    if (q == 0 && tid == 0) accum[0] = 0.f;
}

// ---- Kernel 2: fused transpose+GEMM+argmin+gather+output+loss ---------------
__global__ __launch_bounds__(512) void k_main(
        const v8s* __restrict__ Esw,
        const float* __restrict__ nE,
        const float* __restrict__ z,
        const float* __restrict__ E,
        float* __restrict__ out,
        float* __restrict__ accum) {
    __shared__ union {
        v8s    B[2][2048];          // 2 x 32 KB double-buffer (also A-tile 64KB)
        float4 Eg4[2048];           // epilogue swizzled tile (32 KB)
    } S;
    __shared__ float nEl[1024];
    __shared__ int   idxLds[128];
    __shared__ float w8[8];

    int tid = threadIdx.x;
    int lane = tid & 63, w = tid >> 6;         // 8 waves
    int g = lane >> 4, m = lane & 15;          // MFMA lane coords
    int R0 = blockIdx.x << 7;                  // 128 rows/block
    int b = R0 >> 10, hw0 = R0 & 1023;

    // ---- A-prep: z[b][0..256][hw0..hw0+128] -> swizzled bf16 LDS tile ------
    // Thread (q=tid&31, dblk=tid>>5) loads 16 d-rows x float4 at hw quad 4q,
    // repacks to 8 v8s (4 rows x 2 slots). Swizzle slot^((row^row>>2)&7)
    // spreads both the row%4-strided writes and the row-varying frag reads
    // across all 8 bank-quads (b128 floor, no serialization beyond it).
    {
        int q = tid & 31, dblk = tid >> 5;     // hw = hw0+4q, d base = dblk*16
        const float* zp = z + ((size_t)b << 18) + hw0 + (q << 2);
#pragma unroll
        for (int s = 0; s < 2; s++) {
            float4 L[8];
#pragma unroll
            for (int j = 0; j < 8; j++)
                L[j] = *(const float4*)(zp + (size_t)(((dblk << 4) + (s << 3) + j) << 10));
            const float* Lf = (const float*)L;
            int slot = (dblk << 1) + s;
#pragma unroll
            for (int c = 0; c < 4; c++) {
                union { v8s v; unsigned short u[8]; } pk;
#pragma unroll
                for (int j = 0; j < 8; j++) pk.u[j] = f2bf(Lf[j * 4 + c]);
                int row = (q << 2) + c;
                int sw = slot ^ ((row ^ (row >> 2)) & 7);
                *(v8s*)((char*)&S + (row << 9) + (sw << 4)) = pk.v;
            }
        }
    }
#pragma unroll
    for (int i = 0; i < 2; i++) nEl[tid + i * 512] = nE[tid + i * 512];
    __syncthreads();                           // A-tile resident

    // A frags: 16 rows/wave, from LDS; row norm from the same bf16 values
    // (matches the dot's rounding; loss error ~1e-6 after the 8.4M mean).
    v8s a[8];
    float nrm = 0.f;
    {
        int row = (w << 4) + m;
        int f = (row ^ (row >> 2)) & 7;
#pragma unroll
        for (int dc = 0; dc < 8; dc++) {
            int sw = ((dc << 2) + g) ^ f;
            a[dc] = *(const v8s*)((const char*)&S + (row << 9) + (sw << 4));
        }
#pragma unroll
        for (int dc = 0; dc < 8; dc++) {
            union { v8s v; unsigned short u[8]; } un; un.v = a[dc];
#pragma unroll
            for (int j = 0; j < 8; j++) {
                float v = __uint_as_float((uint32_t)un.u[j] << 16);
                nrm = fmaf(v, v, nrm);
            }
        }
        nrm += __shfl_xor(nrm, 16);            // reduce over g: full ||z_row||^2
        nrm += __shfl_xor(nrm, 32);
    }
    __syncthreads();                           // A-tile consumed; S free for B

    // contiguous staging: chunk = 2048 v8s (32 KB); thread stages j*512+tid
#define STAGE(ch, buf)                                                        \
    {                                                                         \
        _Pragma("unroll")                                                     \
        for (int j = 0; j < 4; j++) {                                         \
            __builtin_amdgcn_global_load_lds(                                 \
                (const __attribute__((address_space(1))) void*)               \
                    (Esw + ((size_t)(ch) << 11) + (j << 9) + (w << 6) + lane),\
                (__attribute__((address_space(3))) void*)                     \
                    &S.B[buf][(j << 9) + (w << 6)],                           \
                16, 0, 0);                                                    \
        }                                                                     \
    }

    float best[4]; int bidx[4];
#pragma unroll
    for (int r = 0; r < 4; r++) { best[r] = 3.4e38f; bidx[r] = 0; }

    STAGE(0, 0);
#pragma unroll 1
    for (int ct = 0; ct < 16; ct++) {
        int cur = ct & 1;
        __syncthreads();                       // chunk ct resident
        if (ct < 15) STAGE(ct + 1, cur ^ 1);
        float ne[4];
#pragma unroll
        for (int t = 0; t < 4; t++) ne[t] = nEl[(ct << 6) + t * 16 + m];
        v4f acc[4];
#pragma unroll
        for (int t = 0; t < 4; t++) acc[t] = (v4f){0.f, 0.f, 0.f, 0.f};
#pragma unroll
        for (int dc = 0; dc < 8; dc++) {       // 4 indep chains/wave
#pragma unroll
            for (int t = 0; t < 4; t++) {
                v8s bf = S.B[cur][t * 512 + dc * 64 + g * 16 + m];
                acc[t] = __builtin_amdgcn_mfma_f32_16x16x32_bf16(a[dc], bf, acc[t], 0, 0, 0);
            }
        }
#pragma unroll
        for (int t = 0; t < 4; t++) {          // ascending code: tie -> low idx
            int code = (ct << 6) + t * 16 + m;
#pragma unroll
            for (int r = 0; r < 4; r++) {
                float s0 = ne[t] - acc[t][r];
                if (s0 < best[r]) { best[r] = s0; bidx[r] = code; }
            }
        }
    }

    // winner reduce over 16 code-columns (pack: min => low score, low idx);
    // loss per row folded in: ||e* - z||^2 = 2*s* + ||z||^2.
    float lsum = 0.f;
#pragma unroll
    for (int r = 0; r < 4; r++) {
        uint32_t sb = __float_as_uint(best[r]);
        sb = (sb & 0x80000000u) ? ~sb : (sb | 0x80000000u);
        unsigned long long pk = ((unsigned long long)sb << 32) | (uint32_t)bidx[r];
#pragma unroll
        for (int off = 1; off < 16; off <<= 1) {
            unsigned long long o = __shfl_xor(pk, off);
            if (o < pk) pk = o;
        }
        float rn = __shfl(nrm, (g << 2) + r);  // norm of row w*16 + g*4 + r
        if (m == 0) {                          // C/D row = g*4 + r
            idxLds[w * 16 + g * 4 + r] = (int)(pk & 0xffffffffu);
            uint32_t t = (uint32_t)(pk >> 32);
            float sw = __uint_as_float((t & 0x80000000u) ? (t & 0x7fffffffu) : ~t);
            lsum += 2.0f * sw + rn;
        }
    }
    __syncthreads();                           // winners visible; B free

    // epilogue: gather E rows + coalesced NCHW writes via XOR-swizzled tile.
    float* ob = out + ((size_t)b << 18);
    int hwl = tid & 31, dq0 = tid >> 5;        // dq0: 0..15
#pragma unroll 1
    for (int ph = 0; ph < 4; ph++) {
#pragma unroll
        for (int i = 0; i < 4; i++) {          // rows w + 8i (wave-uniform)
            int row = w + (i << 3);
            int k = idxLds[(ph << 5) + row];
            float4 v = ((const float4*)(E + ((size_t)k << 8)))[lane];
            S.Eg4[(row << 6) + (lane ^ row)] = v;
        }
        __syncthreads();
        int hwp = hw0 + (ph << 5) + hwl;
#pragma unroll
        for (int i = 0; i < 4; i++) {
            int dq = dq0 + (i << 4);
            float4 ev = S.Eg4[(hwl << 6) + (dq ^ hwl)];
            size_t o = ((size_t)dq << 12) + hwp;        // (4*dq)*1024 + hwp
            ob[o] = ev.x; ob[o + 1024] = ev.y; ob[o + 2048] = ev.z; ob[o + 3072] = ev.w;
        }
        __syncthreads();                        // tile reused next phase
    }
#pragma unroll
    for (int off = 1; off < 64; off <<= 1) lsum += __shfl_xor(lsum, off);
    if (lane == 0) w8[w] = lsum;
    __syncthreads();
    if (tid == 0) {
        float s = 0.f;
#pragma unroll
        for (int i = 0; i < 8; i++) s += w8[i];
        atomicAdd(accum, s);
    }
#undef STAGE
}

// ---- Kernel 3: scalar outputs ----------------------------------------------
__global__ void k_loss(const float* __restrict__ accum, float* __restrict__ out) {
    if (threadIdx.x == 0) {
        float s = accum[0] * (1.0f / 8388608.0f);
        out[8388608] = 1.25f * s;
        out[8388609] = s;
        out[8388610] = s;
    }
}

extern "C" void kernel_launch(void* const* d_in, const int* in_sizes, int n_in,
                              void* d_out, int out_size, void* d_ws, size_t ws_size,
                              hipStream_t stream) {
    const float* z = (const float*)d_in[0];
    const float* E = (const float*)d_in[1];
    char* ws = (char*)d_ws;
    v8s*   Esw   = (v8s*)(ws);                   // 524,288 B
    float* nE    = (float*)(ws + 524288);        //   4,096 B
    float* accum = (float*)(ws + 528384);        //       4 B
    float* out = (float*)d_out;

    hipLaunchKernelGGL(k_prep_e, dim3(64),  dim3(256), 0, stream, E, Esw, nE, accum);
    hipLaunchKernelGGL(k_main,   dim3(256), dim3(512), 0, stream,
                       Esw, nE, z, E, out, accum);
    hipLaunchKernelGGL(k_loss,   dim3(1),   dim3(64),  0, stream, accum, out);
}